// Round 4
// baseline (228.969 us; speedup 1.0000x reference)
//
#include <hip/hip_runtime.h>
#include <hip/hip_bf16.h>

#define NTOT 8192
#define NBSZ 4096
#define DDIM 256
#define NCHUNK 32
#define CHUNK_COLS 256
#define TILE_COLS 32
#define NT (CHUNK_COLS / TILE_COLS)
#define NCLASS 100

#define INV_T 14.285714285714286f
#define EPI_T 1.4285714285714286f
// base-2 folded: exp(logit) = exp2(dot*K1 + same*BIASS)
#define K1 20.609929155556076f      /* INV_T * log2(e) */
#define BIASS -2.0609929155556078f  /* -EPI_T * log2(e) */

typedef __attribute__((ext_vector_type(8))) __bf16 bf16x8;
typedef __attribute__((ext_vector_type(4))) float f32x4;

__device__ __forceinline__ unsigned short f2bf(float x) {
    union { float f; unsigned int u; } a; a.f = x;
    unsigned int r = a.u + 0x7fffu + ((a.u >> 16) & 1u);
    return (unsigned short)(r >> 16);
}

// K1: build bf16 contrast matrix B[8192][256] (view-major) + tiled labels.
// Also zeroes the atomic accumulators (pSe, pPd, out).
__global__ __launch_bounds__(256) void prep_kernel(const float* __restrict__ feat,
                                                   const int* __restrict__ labels,
                                                   unsigned short* __restrict__ Bg,
                                                   int* __restrict__ labT,
                                                   float* __restrict__ pSe,
                                                   float* __restrict__ pPd,
                                                   float* __restrict__ out) {
    const int g = blockIdx.x * 256 + threadIdx.x;   // 8192 rows x 64 lanes
    const int row = g >> 6, t = g & 63;
    const int v = row >> 12, b = row & (NBSZ - 1);
    const float* src = feat + (size_t)(b * 2 + v) * DDIM + t * 4;
    f32x4 val = *(const f32x4*)src;
    ushort4 o;
    o.x = f2bf(val[0]); o.y = f2bf(val[1]); o.z = f2bf(val[2]); o.w = f2bf(val[3]);
    *(ushort4*)(Bg + (size_t)row * DDIM + t * 4) = o;
    if (t == 0) labT[row] = labels[b];
    if (g < NTOT) pSe[g] = 0.f;
    else if (g < 2 * NTOT) pPd[g - NTOT] = 0.f;
    if (g == 2 * NTOT) out[0] = 0.f;
}

// DMA one 32x256 bf16 tile into LDS (linear dest, source pre-swizzled so the
// read-side XOR sees conflict-free layout). 4 x 16B per thread.
__device__ __forceinline__ void stage_tile(const unsigned short* __restrict__ Bg,
                                           unsigned short* buf, int colBase, int tid) {
    #pragma unroll
    for (int it = 0; it < 4; ++it) {
        int c = it * 256 + tid;          // 16B-chunk index, 0..1023
        int brow = c >> 5, bc = c & 31;
        int sc = bc ^ (brow & 7);        // inverse swizzle on SOURCE
        const unsigned short* src = Bg + (size_t)(colBase + brow) * DDIM + sc * 8;
        __builtin_amdgcn_global_load_lds(
            (const __attribute__((address_space(1))) void*)src,
            (__attribute__((address_space(3))) void*)(buf + (size_t)c * 8),
            16, 0, 0);
    }
}

// K2: Gram + fused exp-sum + positive-dot sum. Grid (32 row-blocks, 32 chunks).
__global__ __launch_bounds__(256, 4) void supcon_main(
    const unsigned short* __restrict__ Bg, const int* __restrict__ labT,
    float* __restrict__ pSe, float* __restrict__ pPd)
{
    __shared__ alignas(16) unsigned short btile[2][TILE_COLS * DDIM];  // 2 x 16 KB
    __shared__ int labc_s[CHUNK_COLS];                                 // 1 KB

    const int tid = threadIdx.x;
    const int wid = tid >> 6;
    const int lane = tid & 63;
    const int q = lane >> 4;
    const int r16 = lane & 15;

    const int rowBase = blockIdx.x * 256 + wid * 64;   // wave owns 64 rows
    const int colChunk = blockIdx.y * CHUNK_COLS;

    labc_s[tid] = labT[colChunk + tid];

    // A fragments: 64 rows x K=256 in registers (128 VGPR).
    bf16x8 afr[4][8];
    #pragma unroll
    for (int m = 0; m < 4; ++m) {
        const unsigned short* ap = Bg + (size_t)(rowBase + m * 16 + r16) * DDIM + q * 8;
        #pragma unroll
        for (int ks = 0; ks < 8; ++ks)
            afr[m][ks] = *(const bf16x8*)(ap + ks * 32);
    }
    int labrow[4][4];
    #pragma unroll
    for (int m = 0; m < 4; ++m)
        #pragma unroll
        for (int r = 0; r < 4; ++r)
            labrow[m][r] = labT[rowBase + m * 16 + q * 4 + r];

    float se[4][4], pd[4][4];
    #pragma unroll
    for (int m = 0; m < 4; ++m)
        #pragma unroll
        for (int r = 0; r < 4; ++r) { se[m][r] = 0.f; pd[m][r] = 0.f; }

    stage_tile(Bg, btile[0], colChunk, tid);
    __syncthreads();   // drains vmcnt -> tile 0 ready

    for (int tile = 0; tile < NT; ++tile) {
        // issue next tile's DMA before compute; stays in flight under MFMA
        if (tile + 1 < NT)
            stage_tile(Bg, btile[(tile + 1) & 1], colChunk + (tile + 1) * TILE_COLS, tid);

        const unsigned short* bt = btile[tile & 1];
        f32x4 acc[4][2];
        #pragma unroll
        for (int m = 0; m < 4; ++m) { acc[m][0] = (f32x4)0.f; acc[m][1] = (f32x4)0.f; }

        __builtin_amdgcn_s_setprio(1);
        #pragma unroll
        for (int ks = 0; ks < 8; ++ks) {
            const int cx = (ks * 4 + q) ^ (r16 & 7);
            bf16x8 bq0 = *(const bf16x8*)(bt + r16 * DDIM + cx * 8);
            bf16x8 bq1 = *(const bf16x8*)(bt + (16 + r16) * DDIM + cx * 8);
            #pragma unroll
            for (int m = 0; m < 4; ++m) {
                acc[m][0] = __builtin_amdgcn_mfma_f32_16x16x32_bf16(afr[m][ks], bq0, acc[m][0], 0, 0, 0);
                acc[m][1] = __builtin_amdgcn_mfma_f32_16x16x32_bf16(afr[m][ks], bq1, acc[m][1], 0, 0, 0);
            }
        }
        __builtin_amdgcn_s_setprio(0);

        const int colBase = colChunk + tile * TILE_COLS;
        const int lc0 = labc_s[tile * TILE_COLS + r16];
        const int lc1 = labc_s[tile * TILE_COLS + 16 + r16];
        const bool diagT = ((unsigned)(colBase - rowBase)) < 64u;
        if (!diagT) {
            #pragma unroll
            for (int n = 0; n < 2; ++n) {
                const int lc = n ? lc1 : lc0;
                #pragma unroll
                for (int m = 0; m < 4; ++m)
                    #pragma unroll
                    for (int r = 0; r < 4; ++r) {
                        const bool same = (lc == labrow[m][r]);
                        float a = acc[m][n][r];
                        float t = fmaf(a, K1, same ? BIASS : 0.f);
                        se[m][r] += __builtin_amdgcn_exp2f(t);
                        pd[m][r] += same ? a : 0.f;
                    }
            }
        } else {
            #pragma unroll
            for (int n = 0; n < 2; ++n) {
                const int lc = n ? lc1 : lc0;
                const int gcol = colBase + n * 16 + r16;
                #pragma unroll
                for (int m = 0; m < 4; ++m)
                    #pragma unroll
                    for (int r = 0; r < 4; ++r) {
                        const int grow = rowBase + m * 16 + q * 4 + r;
                        const bool same = (lc == labrow[m][r]);
                        const bool keep = (grow != gcol);
                        float a = acc[m][n][r];
                        float t = fmaf(a, K1, same ? BIASS : 0.f);
                        float e = __builtin_amdgcn_exp2f(t);
                        se[m][r] += keep ? e : 0.f;
                        pd[m][r] += (same && keep) ? a : 0.f;
                    }
            }
        }
        __syncthreads();   // drains DMA (next tile ready) + LDS reads done
    }

    // merge the 16 lanes (r16 bits) sharing each row
    #pragma unroll
    for (int mask = 1; mask <= 8; mask <<= 1)
        #pragma unroll
        for (int m = 0; m < 4; ++m)
            #pragma unroll
            for (int r = 0; r < 4; ++r) {
                se[m][r] += __shfl_xor(se[m][r], mask);
                pd[m][r] += __shfl_xor(pd[m][r], mask);
            }
    if (r16 == 0) {
        #pragma unroll
        for (int m = 0; m < 4; ++m)
            #pragma unroll
            for (int r = 0; r < 4; ++r) {
                const int row = rowBase + m * 16 + q * 4 + r;
                atomicAdd(&pSe[row], se[m][r]);
                atomicAdd(&pPd[row], pd[m][r]);
            }
    }
}

// K3: per-row loss + block partial + atomic accumulate to out. 32 x 256.
__global__ __launch_bounds__(256) void finalize_kernel(
    const int* __restrict__ labT, const float* __restrict__ pSe,
    const float* __restrict__ pPd, float* __restrict__ out)
{
    __shared__ int hist[NCLASS];
    const int t = threadIdx.x;
    if (t < NCLASS) hist[t] = 0;
    __syncthreads();
    #pragma unroll
    for (int i = 0; i < NTOT / 256; ++i)
        atomicAdd(&hist[labT[i * 256 + t]], 1);   // coalesced label reads
    __syncthreads();

    const int row = blockIdx.x * 256 + t;
    const int lab = labT[row];
    const float se = pSe[row];
    const float pd = pPd[row];
    const float pc = (float)(hist[lab] - 1);
    float loss = EPI_T + __logf(se) - INV_T * pd / pc;

    #pragma unroll
    for (int mask = 1; mask < 64; mask <<= 1) loss += __shfl_xor(loss, mask);
    __shared__ float red[4];
    if ((t & 63) == 0) red[t >> 6] = loss;
    __syncthreads();
    if (t == 0)
        atomicAdd(out, (red[0] + red[1] + red[2] + red[3]) * (1.f / (float)NTOT));
}

extern "C" void kernel_launch(void* const* d_in, const int* in_sizes, int n_in,
                              void* d_out, int out_size, void* d_ws, size_t ws_size,
                              hipStream_t stream) {
    const float* feat = (const float*)d_in[0];
    const int* labels = (const int*)d_in[1];
    float* out = (float*)d_out;

    char* ws = (char*)d_ws;
    unsigned short* Bg = (unsigned short*)ws;                        // 4 MB
    int* labT = (int*)(ws + (4u << 20));                             // 32 KB
    float* pSe = (float*)(ws + (4u << 20) + (64u << 10));            // 32 KB
    float* pPd = (float*)(ws + (4u << 20) + (128u << 10));           // 32 KB

    prep_kernel<<<2048, 256, 0, stream>>>(feat, labels, Bg, labT, pSe, pPd, out);
    dim3 grid(32, NCHUNK);
    supcon_main<<<grid, 256, 0, stream>>>(Bg, labT, pSe, pPd);
    finalize_kernel<<<32, 256, 0, stream>>>(labT, pSe, pPd, out);
}

// Round 5
// 97.761 us; speedup vs baseline: 2.3421x; 2.3421x over previous
//
#include <hip/hip_runtime.h>
#include <hip/hip_bf16.h>

#define NTOT 8192
#define NBSZ 4096
#define DDIM 256
#define NCHUNK 16
#define CHUNK_COLS 512
#define TILE_COLS 32
#define NT (CHUNK_COLS / TILE_COLS)
#define NCLASS 100

#define INV_T 14.285714285714286f
#define EPI_T 1.4285714285714286f
// base-2 folded: exp(logit) = exp2(dot*K1 + same*BIASS)
#define K1 20.609929155556076f      /* INV_T * log2(e) */
#define BIASS -2.0609929155556078f  /* -EPI_T * log2(e) */

typedef __attribute__((ext_vector_type(8))) __bf16 bf16x8;
typedef __attribute__((ext_vector_type(4))) float f32x4;

__device__ __forceinline__ unsigned short f2bf(float x) {
    union { float f; unsigned int u; } a; a.f = x;
    unsigned int r = a.u + 0x7fffu + ((a.u >> 16) & 1u);
    return (unsigned short)(r >> 16);
}

// K1: build bf16 contrast matrix B[8192][256] (view-major) + tiled labels.
// Also zeroes the atomic accumulators (pSe, pPd, out).
__global__ __launch_bounds__(256) void prep_kernel(const float* __restrict__ feat,
                                                   const int* __restrict__ labels,
                                                   unsigned short* __restrict__ Bg,
                                                   int* __restrict__ labT,
                                                   float* __restrict__ pSe,
                                                   float* __restrict__ pPd,
                                                   float* __restrict__ out) {
    const int g = blockIdx.x * 256 + threadIdx.x;   // 8192 rows x 64 lanes
    const int row = g >> 6, t = g & 63;
    const int v = row >> 12, b = row & (NBSZ - 1);
    const float* src = feat + (size_t)(b * 2 + v) * DDIM + t * 4;
    f32x4 val = *(const f32x4*)src;
    ushort4 o;
    o.x = f2bf(val[0]); o.y = f2bf(val[1]); o.z = f2bf(val[2]); o.w = f2bf(val[3]);
    *(ushort4*)(Bg + (size_t)row * DDIM + t * 4) = o;
    if (t == 0) labT[row] = labels[b];
    if (g < NTOT) pSe[g] = 0.f;
    else if (g < 2 * NTOT) pPd[g - NTOT] = 0.f;
    if (g == 2 * NTOT) out[0] = 0.f;
}

// K2: Gram + fused exp-sum + positive-dot sum. NO LDS, NO barriers:
// B-fragments read directly from global (L1/L2-resident), waves free-run.
// Grid (32 row-blocks, 16 chunks), 256 thr; wave owns 64 rows x 512 cols.
__global__ __launch_bounds__(256, 2) void supcon_main(
    const unsigned short* __restrict__ Bg, const int* __restrict__ labT,
    float* __restrict__ pSe, float* __restrict__ pPd)
{
    const int tid = threadIdx.x;
    const int wid = tid >> 6;
    const int lane = tid & 63;
    const int q = lane >> 4;       // 0..3 -> k-subchunk
    const int r16 = lane & 15;

    const int rowBase = blockIdx.x * 256 + wid * 64;   // wave owns 64 rows
    const int colChunk = blockIdx.y * CHUNK_COLS;

    // A fragments: 64 rows x K=256 in registers (128 VGPR).
    bf16x8 afr[4][8];
    #pragma unroll
    for (int m = 0; m < 4; ++m) {
        const unsigned short* ap = Bg + (size_t)(rowBase + m * 16 + r16) * DDIM + q * 8;
        #pragma unroll
        for (int ks = 0; ks < 8; ++ks)
            afr[m][ks] = *(const bf16x8*)(ap + ks * 32);
    }
    int labrow[4][4];
    #pragma unroll
    for (int m = 0; m < 4; ++m)
        #pragma unroll
        for (int r = 0; r < 4; ++r)
            labrow[m][r] = labT[rowBase + m * 16 + q * 4 + r];

    float se[4][4], pd[4][4];
    #pragma unroll
    for (int m = 0; m < 4; ++m)
        #pragma unroll
        for (int r = 0; r < 4; ++r) { se[m][r] = 0.f; pd[m][r] = 0.f; }

    for (int tile = 0; tile < NT; ++tile) {
        const int colBase = colChunk + tile * TILE_COLS;
        // B-fragment base pointers for this tile (rows colBase+r16, +16+r16)
        const unsigned short* b0 = Bg + (size_t)(colBase + r16) * DDIM + q * 8;
        const unsigned short* b1 = Bg + (size_t)(colBase + 16 + r16) * DDIM + q * 8;
        const int lc0 = labT[colBase + r16];
        const int lc1 = labT[colBase + 16 + r16];

        f32x4 acc[4][2];
        #pragma unroll
        for (int m = 0; m < 4; ++m) { acc[m][0] = (f32x4)0.f; acc[m][1] = (f32x4)0.f; }

        #pragma unroll
        for (int ks = 0; ks < 8; ++ks) {
            bf16x8 bq0 = *(const bf16x8*)(b0 + ks * 32);   // imm-offset loads
            bf16x8 bq1 = *(const bf16x8*)(b1 + ks * 32);
            #pragma unroll
            for (int m = 0; m < 4; ++m) {
                acc[m][0] = __builtin_amdgcn_mfma_f32_16x16x32_bf16(afr[m][ks], bq0, acc[m][0], 0, 0, 0);
                acc[m][1] = __builtin_amdgcn_mfma_f32_16x16x32_bf16(afr[m][ks], bq1, acc[m][1], 0, 0, 0);
            }
        }

        const bool diagT = ((unsigned)(colBase - rowBase)) < 64u;
        if (!diagT) {
            #pragma unroll
            for (int n = 0; n < 2; ++n) {
                const int lc = n ? lc1 : lc0;
                #pragma unroll
                for (int m = 0; m < 4; ++m)
                    #pragma unroll
                    for (int r = 0; r < 4; ++r) {
                        const bool same = (lc == labrow[m][r]);
                        float a = acc[m][n][r];
                        float t = fmaf(a, K1, same ? BIASS : 0.f);
                        se[m][r] += __builtin_amdgcn_exp2f(t);
                        pd[m][r] += same ? a : 0.f;
                    }
            }
        } else {
            #pragma unroll
            for (int n = 0; n < 2; ++n) {
                const int lc = n ? lc1 : lc0;
                const int gcol = colBase + n * 16 + r16;
                #pragma unroll
                for (int m = 0; m < 4; ++m)
                    #pragma unroll
                    for (int r = 0; r < 4; ++r) {
                        const int grow = rowBase + m * 16 + q * 4 + r;
                        const bool same = (lc == labrow[m][r]);
                        const bool keep = (grow != gcol);
                        float a = acc[m][n][r];
                        float t = fmaf(a, K1, same ? BIASS : 0.f);
                        float e = __builtin_amdgcn_exp2f(t);
                        se[m][r] += keep ? e : 0.f;
                        pd[m][r] += (same && keep) ? a : 0.f;
                    }
            }
        }
    }

    // merge the 16 lanes (r16 bits) sharing each row
    #pragma unroll
    for (int mask = 1; mask <= 8; mask <<= 1)
        #pragma unroll
        for (int m = 0; m < 4; ++m)
            #pragma unroll
            for (int r = 0; r < 4; ++r) {
                se[m][r] += __shfl_xor(se[m][r], mask);
                pd[m][r] += __shfl_xor(pd[m][r], mask);
            }
    if (r16 == 0) {
        #pragma unroll
        for (int m = 0; m < 4; ++m)
            #pragma unroll
            for (int r = 0; r < 4; ++r) {
                const int row = rowBase + m * 16 + q * 4 + r;
                atomicAdd(&pSe[row], se[m][r]);
                atomicAdd(&pPd[row], pd[m][r]);
            }
    }
}

// K3: per-row loss + block partial + atomic accumulate to out. 32 x 256.
__global__ __launch_bounds__(256) void finalize_kernel(
    const int* __restrict__ labT, const float* __restrict__ pSe,
    const float* __restrict__ pPd, float* __restrict__ out)
{
    __shared__ int hist[NCLASS];
    const int t = threadIdx.x;
    if (t < NCLASS) hist[t] = 0;
    __syncthreads();
    #pragma unroll
    for (int i = 0; i < NTOT / 256; ++i)
        atomicAdd(&hist[labT[i * 256 + t]], 1);   // coalesced label reads
    __syncthreads();

    const int row = blockIdx.x * 256 + t;
    const int lab = labT[row];
    const float se = pSe[row];
    const float pd = pPd[row];
    const float pc = (float)(hist[lab] - 1);
    float loss = EPI_T + __logf(se) - INV_T * pd / pc;

    #pragma unroll
    for (int mask = 1; mask < 64; mask <<= 1) loss += __shfl_xor(loss, mask);
    __shared__ float red[4];
    if ((t & 63) == 0) red[t >> 6] = loss;
    __syncthreads();
    if (t == 0)
        atomicAdd(out, (red[0] + red[1] + red[2] + red[3]) * (1.f / (float)NTOT));
}

extern "C" void kernel_launch(void* const* d_in, const int* in_sizes, int n_in,
                              void* d_out, int out_size, void* d_ws, size_t ws_size,
                              hipStream_t stream) {
    const float* feat = (const float*)d_in[0];
    const int* labels = (const int*)d_in[1];
    float* out = (float*)d_out;

    char* ws = (char*)d_ws;
    unsigned short* Bg = (unsigned short*)ws;                        // 4 MB
    int* labT = (int*)(ws + (4u << 20));                             // 32 KB
    float* pSe = (float*)(ws + (4u << 20) + (64u << 10));            // 32 KB
    float* pPd = (float*)(ws + (4u << 20) + (128u << 10));           // 32 KB

    prep_kernel<<<2048, 256, 0, stream>>>(feat, labels, Bg, labT, pSe, pPd, out);
    dim3 grid(32, NCHUNK);
    supcon_main<<<grid, 256, 0, stream>>>(Bg, labT, pSe, pPd);
    finalize_kernel<<<32, 256, 0, stream>>>(labT, pSe, pPd, out);
}

// Round 6
// 90.148 us; speedup vs baseline: 2.5399x; 1.0844x over previous
//
#include <hip/hip_runtime.h>
#include <hip/hip_bf16.h>

#define NTOT 8192
#define NBSZ 4096
#define DDIM 256
#define NCHUNK 32
#define CHUNK_COLS 256
#define TILE_COLS 32
#define NT (CHUNK_COLS / TILE_COLS)
#define NCLASS 100

#define INV_T 14.285714285714286f
#define EPI_T 1.4285714285714286f
// base-2 folded: exp(logit) = exp2(dot*K1 + same*BIASS)
#define K1 20.609929155556076f      /* INV_T * log2(e) */
#define BIASS -2.0609929155556078f  /* -EPI_T * log2(e) */

typedef __attribute__((ext_vector_type(8))) __bf16 bf16x8;
typedef __attribute__((ext_vector_type(4))) float f32x4;

__device__ __forceinline__ unsigned short f2bf(float x) {
    union { float f; unsigned int u; } a; a.f = x;
    unsigned int r = a.u + 0x7fffu + ((a.u >> 16) & 1u);
    return (unsigned short)(r >> 16);
}

// K1: build bf16 contrast matrix B[8192][256] (view-major) + tiled labels.
// Also zeroes the atomic accumulators (pSe, pPd, out).
__global__ __launch_bounds__(256) void prep_kernel(const float* __restrict__ feat,
                                                   const int* __restrict__ labels,
                                                   unsigned short* __restrict__ Bg,
                                                   int* __restrict__ labT,
                                                   float* __restrict__ pSe,
                                                   float* __restrict__ pPd,
                                                   float* __restrict__ out) {
    const int g = blockIdx.x * 256 + threadIdx.x;   // 8192 rows x 64 lanes
    const int row = g >> 6, t = g & 63;
    const int v = row >> 12, b = row & (NBSZ - 1);
    const float* src = feat + (size_t)(b * 2 + v) * DDIM + t * 4;
    f32x4 val = *(const f32x4*)src;
    ushort4 o;
    o.x = f2bf(val[0]); o.y = f2bf(val[1]); o.z = f2bf(val[2]); o.w = f2bf(val[3]);
    *(ushort4*)(Bg + (size_t)row * DDIM + t * 4) = o;
    if (t == 0) labT[row] = labels[b];
    if (g < NTOT) pSe[g] = 0.f;
    else if (g < 2 * NTOT) pPd[g - NTOT] = 0.f;
    if (g == 2 * NTOT) out[0] = 0.f;
}

// DMA one 32x256 bf16 tile into LDS (linear dest, source pre-swizzled so the
// read-side XOR sees conflict-free layout). 4 x 16B per thread.
__device__ __forceinline__ void stage_tile(const unsigned short* __restrict__ Bg,
                                           unsigned short* buf, int colBase, int tid) {
    #pragma unroll
    for (int it = 0; it < 4; ++it) {
        int c = it * 256 + tid;          // 16B-chunk index, 0..1023
        int brow = c >> 5, bc = c & 31;
        int sc = bc ^ (brow & 7);        // inverse swizzle on SOURCE
        const unsigned short* src = Bg + (size_t)(colBase + brow) * DDIM + sc * 8;
        __builtin_amdgcn_global_load_lds(
            (const __attribute__((address_space(1))) void*)src,
            (__attribute__((address_space(3))) void*)(buf + (size_t)c * 8),
            16, 0, 0);
    }
}

// K2: Gram + fused exp-sum + positive-dot sum. Grid (32 row-blocks, 32 chunks)
// = 1024 blocks = 4 blocks/CU (128 VGPR, 33 KB LDS both allow 4).
__global__ __launch_bounds__(256, 2) void supcon_main(
    const unsigned short* __restrict__ Bg, const int* __restrict__ labT,
    float* __restrict__ pSe, float* __restrict__ pPd)
{
    __shared__ alignas(16) unsigned short btile[2][TILE_COLS * DDIM];  // 2 x 16 KB
    __shared__ int labc_s[CHUNK_COLS];                                 // 1 KB

    const int tid = threadIdx.x;
    const int wid = tid >> 6;
    const int lane = tid & 63;
    const int q = lane >> 4;
    const int r16 = lane & 15;

    const int rowBase = blockIdx.x * 256 + wid * 64;   // wave owns 64 rows
    const int colChunk = blockIdx.y * CHUNK_COLS;

    labc_s[tid] = labT[colChunk + tid];

    // A fragments: 64 rows x K=256 in registers (128 VGPR).
    bf16x8 afr[4][8];
    #pragma unroll
    for (int m = 0; m < 4; ++m) {
        const unsigned short* ap = Bg + (size_t)(rowBase + m * 16 + r16) * DDIM + q * 8;
        #pragma unroll
        for (int ks = 0; ks < 8; ++ks)
            afr[m][ks] = *(const bf16x8*)(ap + ks * 32);
    }
    int labrow[4][4];
    #pragma unroll
    for (int m = 0; m < 4; ++m)
        #pragma unroll
        for (int r = 0; r < 4; ++r)
            labrow[m][r] = labT[rowBase + m * 16 + q * 4 + r];

    float se[4][4], pd[4][4];
    #pragma unroll
    for (int m = 0; m < 4; ++m)
        #pragma unroll
        for (int r = 0; r < 4; ++r) { se[m][r] = 0.f; pd[m][r] = 0.f; }

    stage_tile(Bg, btile[0], colChunk, tid);
    __syncthreads();   // drains vmcnt -> tile 0 ready

    for (int tile = 0; tile < NT; ++tile) {
        // issue next tile's DMA before compute; stays in flight under MFMA
        if (tile + 1 < NT)
            stage_tile(Bg, btile[(tile + 1) & 1], colChunk + (tile + 1) * TILE_COLS, tid);

        const unsigned short* bt = btile[tile & 1];
        f32x4 acc[4][2];
        #pragma unroll
        for (int m = 0; m < 4; ++m) { acc[m][0] = (f32x4)0.f; acc[m][1] = (f32x4)0.f; }

        __builtin_amdgcn_s_setprio(1);
        #pragma unroll
        for (int ks = 0; ks < 8; ++ks) {
            const int cx = (ks * 4 + q) ^ (r16 & 7);
            bf16x8 bq0 = *(const bf16x8*)(bt + r16 * DDIM + cx * 8);
            bf16x8 bq1 = *(const bf16x8*)(bt + (16 + r16) * DDIM + cx * 8);
            #pragma unroll
            for (int m = 0; m < 4; ++m) {
                acc[m][0] = __builtin_amdgcn_mfma_f32_16x16x32_bf16(afr[m][ks], bq0, acc[m][0], 0, 0, 0);
                acc[m][1] = __builtin_amdgcn_mfma_f32_16x16x32_bf16(afr[m][ks], bq1, acc[m][1], 0, 0, 0);
            }
        }
        __builtin_amdgcn_s_setprio(0);

        const int colBase = colChunk + tile * TILE_COLS;
        const int lc0 = labc_s[tile * TILE_COLS + r16];
        const int lc1 = labc_s[tile * TILE_COLS + 16 + r16];
        const bool diagT = ((unsigned)(colBase - rowBase)) < 64u;
        if (!diagT) {
            #pragma unroll
            for (int n = 0; n < 2; ++n) {
                const int lc = n ? lc1 : lc0;
                #pragma unroll
                for (int m = 0; m < 4; ++m)
                    #pragma unroll
                    for (int r = 0; r < 4; ++r) {
                        const bool same = (lc == labrow[m][r]);
                        float a = acc[m][n][r];
                        float t = fmaf(a, K1, same ? BIASS : 0.f);
                        se[m][r] += __builtin_amdgcn_exp2f(t);
                        pd[m][r] += same ? a : 0.f;
                    }
            }
        } else {
            #pragma unroll
            for (int n = 0; n < 2; ++n) {
                const int lc = n ? lc1 : lc0;
                const int gcol = colBase + n * 16 + r16;
                #pragma unroll
                for (int m = 0; m < 4; ++m)
                    #pragma unroll
                    for (int r = 0; r < 4; ++r) {
                        const int grow = rowBase + m * 16 + q * 4 + r;
                        const bool same = (lc == labrow[m][r]);
                        const bool keep = (grow != gcol);
                        float a = acc[m][n][r];
                        float t = fmaf(a, K1, same ? BIASS : 0.f);
                        float e = __builtin_amdgcn_exp2f(t);
                        se[m][r] += keep ? e : 0.f;
                        pd[m][r] += (same && keep) ? a : 0.f;
                    }
            }
        }
        __syncthreads();   // drains DMA (next tile ready) + LDS reads done
    }

    // merge the 16 lanes (r16 bits) sharing each row
    #pragma unroll
    for (int mask = 1; mask <= 8; mask <<= 1)
        #pragma unroll
        for (int m = 0; m < 4; ++m)
            #pragma unroll
            for (int r = 0; r < 4; ++r) {
                se[m][r] += __shfl_xor(se[m][r], mask);
                pd[m][r] += __shfl_xor(pd[m][r], mask);
            }
    if (r16 == 0) {
        #pragma unroll
        for (int m = 0; m < 4; ++m)
            #pragma unroll
            for (int r = 0; r < 4; ++r) {
                const int row = rowBase + m * 16 + q * 4 + r;
                atomicAdd(&pSe[row], se[m][r]);
                atomicAdd(&pPd[row], pd[m][r]);
            }
    }
}

// K3: per-row loss + block partial + atomic accumulate to out. 32 x 256.
__global__ __launch_bounds__(256) void finalize_kernel(
    const int* __restrict__ labT, const float* __restrict__ pSe,
    const float* __restrict__ pPd, float* __restrict__ out)
{
    __shared__ int hist[NCLASS];
    const int t = threadIdx.x;
    if (t < NCLASS) hist[t] = 0;
    __syncthreads();
    #pragma unroll
    for (int i = 0; i < NTOT / 256; ++i)
        atomicAdd(&hist[labT[i * 256 + t]], 1);   // coalesced label reads
    __syncthreads();

    const int row = blockIdx.x * 256 + t;
    const int lab = labT[row];
    const float se = pSe[row];
    const float pd = pPd[row];
    const float pc = (float)(hist[lab] - 1);
    float loss = EPI_T + __logf(se) - INV_T * pd / pc;

    #pragma unroll
    for (int mask = 1; mask < 64; mask <<= 1) loss += __shfl_xor(loss, mask);
    __shared__ float red[4];
    if ((t & 63) == 0) red[t >> 6] = loss;
    __syncthreads();
    if (t == 0)
        atomicAdd(out, (red[0] + red[1] + red[2] + red[3]) * (1.f / (float)NTOT));
}

extern "C" void kernel_launch(void* const* d_in, const int* in_sizes, int n_in,
                              void* d_out, int out_size, void* d_ws, size_t ws_size,
                              hipStream_t stream) {
    const float* feat = (const float*)d_in[0];
    const int* labels = (const int*)d_in[1];
    float* out = (float*)d_out;

    char* ws = (char*)d_ws;
    unsigned short* Bg = (unsigned short*)ws;                        // 4 MB
    int* labT = (int*)(ws + (4u << 20));                             // 32 KB
    float* pSe = (float*)(ws + (4u << 20) + (64u << 10));            // 32 KB
    float* pPd = (float*)(ws + (4u << 20) + (128u << 10));           // 32 KB

    prep_kernel<<<2048, 256, 0, stream>>>(feat, labels, Bg, labT, pSe, pPd, out);
    dim3 grid(32, NCHUNK);
    supcon_main<<<grid, 256, 0, stream>>>(Bg, labT, pSe, pPd);
    finalize_kernel<<<32, 256, 0, stream>>>(labT, pSe, pPd, out);
}

// Round 7
// 89.049 us; speedup vs baseline: 2.5713x; 1.0123x over previous
//
#include <hip/hip_runtime.h>
#include <hip/hip_bf16.h>

#define NTOT 8192
#define NBSZ 4096
#define DDIM 256
#define NCHUNK 16
#define CHUNK_COLS 512
#define TILE_COLS 32
#define NT (CHUNK_COLS / TILE_COLS)
#define NCLASS 100

#define INV_T 14.285714285714286f
#define EPI_T 1.4285714285714286f
// base-2 folded: exp(logit) = exp2(dot*K1 + same*BIASS)
#define K1 20.609929155556076f      /* INV_T * log2(e) */
#define BIASS -2.0609929155556078f  /* -EPI_T * log2(e) */

typedef __attribute__((ext_vector_type(8))) __bf16 bf16x8;
typedef __attribute__((ext_vector_type(4))) float f32x4;

__device__ __forceinline__ unsigned short f2bf(float x) {
    union { float f; unsigned int u; } a; a.f = x;
    unsigned int r = a.u + 0x7fffu + ((a.u >> 16) & 1u);
    return (unsigned short)(r >> 16);
}
__device__ __forceinline__ float bf2f(unsigned short u) {
    union { unsigned int u; float f; } a; a.u = ((unsigned int)u) << 16;
    return a.f;
}

// K1: build bf16 contrast matrix B[8192][256] (view-major) + tiled labels; zero out[0].
__global__ __launch_bounds__(256) void prep_kernel(const float* __restrict__ feat,
                                                   const int* __restrict__ labels,
                                                   unsigned short* __restrict__ Bg,
                                                   int* __restrict__ labT,
                                                   float* __restrict__ out) {
    const int g = blockIdx.x * 256 + threadIdx.x;   // 8192 rows x 64 lanes
    const int row = g >> 6, t = g & 63;
    const int v = row >> 12, b = row & (NBSZ - 1);
    const float* src = feat + (size_t)(b * 2 + v) * DDIM + t * 4;
    f32x4 val = *(const f32x4*)src;
    ushort4 o;
    o.x = f2bf(val[0]); o.y = f2bf(val[1]); o.z = f2bf(val[2]); o.w = f2bf(val[3]);
    *(ushort4*)(Bg + (size_t)row * DDIM + t * 4) = o;
    if (t == 0) labT[row] = labels[b];
    if (g == 0) out[0] = 0.f;
}

// K2: per-class feature sums S[100][256] (fp32), deterministic compaction (R1-proven).
__global__ __launch_bounds__(256) void classsum_kernel(const unsigned short* __restrict__ Bg,
                                                       const int* __restrict__ labT,
                                                       float* __restrict__ S) {
    const int c = blockIdx.x, t = threadIdx.x;
    __shared__ int cnts[256];
    __shared__ short list[2048];
    __shared__ int tot_s;
    const int base = t * 32;
    int local = 0;
    for (int i = 0; i < 32; ++i) local += (labT[base + i] == c);
    cnts[t] = local;
    __syncthreads();
    int off = 0;
    for (int i = 0; i < t; ++i) off += cnts[i];
    for (int i = 0; i < 32; ++i)
        if (labT[base + i] == c) list[off++] = (short)(base + i);
    if (t == 255) tot_s = off;
    __syncthreads();
    const int tot = tot_s;
    float s = 0.f;
    for (int j = 0; j < tot; ++j)
        s += bf2f(Bg[(size_t)((unsigned short)list[j]) * DDIM + t]);
    S[c * DDIM + t] = s;
}

// DMA one 32x256 bf16 tile into LDS (linear dest, source pre-swizzled so the
// read-side XOR sees conflict-free layout). 4 x 16B per thread.
__device__ __forceinline__ void stage_tile(const unsigned short* __restrict__ Bg,
                                           unsigned short* buf, int colBase, int tid) {
    #pragma unroll
    for (int it = 0; it < 4; ++it) {
        int c = it * 256 + tid;          // 16B-chunk index, 0..1023
        int brow = c >> 5, bc = c & 31;
        int sc = bc ^ (brow & 7);        // inverse swizzle on SOURCE
        const unsigned short* src = Bg + (size_t)(colBase + brow) * DDIM + sc * 8;
        __builtin_amdgcn_global_load_lds(
            (const __attribute__((address_space(1))) void*)src,
            (__attribute__((address_space(3))) void*)(buf + (size_t)c * 8),
            16, 0, 0);
    }
}

// K3: Gram + fused exp-sum. Wave owns 32 rows (M_rep=2, small reg footprint);
// block = 4 waves = 128 rows. Grid (64 row-blocks, 16 chunks) = 1024 blocks
// -> 4 blocks/CU, one generation. Uniform epilogue (no diag branch, no pd).
__global__ __launch_bounds__(256) void supcon_main(
    const unsigned short* __restrict__ Bg, const int* __restrict__ labT,
    float* __restrict__ pSe)
{
    __shared__ alignas(16) unsigned short btile[2][TILE_COLS * DDIM];  // 2 x 16 KB
    __shared__ int labc_s[CHUNK_COLS];                                 // 2 KB

    const int tid = threadIdx.x;
    const int wid = tid >> 6;
    const int lane = tid & 63;
    const int q = lane >> 4;
    const int r16 = lane & 15;

    const int rowBase = blockIdx.x * 128 + wid * 32;   // wave owns 32 rows
    const int colChunk = blockIdx.y * CHUNK_COLS;

    labc_s[tid] = labT[colChunk + tid];
    labc_s[256 + tid] = labT[colChunk + 256 + tid];

    // A fragments: 32 rows x K=256 in registers (32 VGPR).
    bf16x8 afr[2][8];
    #pragma unroll
    for (int m = 0; m < 2; ++m) {
        const unsigned short* ap = Bg + (size_t)(rowBase + m * 16 + r16) * DDIM + q * 8;
        #pragma unroll
        for (int ks = 0; ks < 8; ++ks)
            afr[m][ks] = *(const bf16x8*)(ap + ks * 32);
    }
    int labrow[2][4];
    #pragma unroll
    for (int m = 0; m < 2; ++m)
        #pragma unroll
        for (int r = 0; r < 4; ++r)
            labrow[m][r] = labT[rowBase + m * 16 + q * 4 + r];

    float se[2][4];
    #pragma unroll
    for (int m = 0; m < 2; ++m)
        #pragma unroll
        for (int r = 0; r < 4; ++r) se[m][r] = 0.f;

    stage_tile(Bg, btile[0], colChunk, tid);
    __syncthreads();   // drains vmcnt -> tile 0 ready

    for (int tile = 0; tile < NT; ++tile) {
        if (tile + 1 < NT)
            stage_tile(Bg, btile[(tile + 1) & 1], colChunk + (tile + 1) * TILE_COLS, tid);

        const unsigned short* bt = btile[tile & 1];
        f32x4 acc[2][2];
        #pragma unroll
        for (int m = 0; m < 2; ++m) { acc[m][0] = (f32x4)0.f; acc[m][1] = (f32x4)0.f; }

        __builtin_amdgcn_s_setprio(1);
        #pragma unroll
        for (int ks = 0; ks < 8; ++ks) {
            const int cx = (ks * 4 + q) ^ (r16 & 7);
            bf16x8 bq0 = *(const bf16x8*)(bt + r16 * DDIM + cx * 8);
            bf16x8 bq1 = *(const bf16x8*)(bt + (16 + r16) * DDIM + cx * 8);
            #pragma unroll
            for (int m = 0; m < 2; ++m) {
                acc[m][0] = __builtin_amdgcn_mfma_f32_16x16x32_bf16(afr[m][ks], bq0, acc[m][0], 0, 0, 0);
                acc[m][1] = __builtin_amdgcn_mfma_f32_16x16x32_bf16(afr[m][ks], bq1, acc[m][1], 0, 0, 0);
            }
        }
        __builtin_amdgcn_s_setprio(0);

        const int lc0 = labc_s[tile * TILE_COLS + r16];
        const int lc1 = labc_s[tile * TILE_COLS + 16 + r16];
        #pragma unroll
        for (int n = 0; n < 2; ++n) {
            const int lc = n ? lc1 : lc0;
            #pragma unroll
            for (int m = 0; m < 2; ++m)
                #pragma unroll
                for (int r = 0; r < 4; ++r) {
                    float t = fmaf(acc[m][n][r], K1, (lc == labrow[m][r]) ? BIASS : 0.f);
                    se[m][r] += __builtin_amdgcn_exp2f(t);
                }
        }
        __syncthreads();   // drains DMA (next tile ready) + LDS reads done
    }

    // merge the 16 lanes (r16 bits) sharing each row
    #pragma unroll
    for (int mask = 1; mask <= 8; mask <<= 1)
        #pragma unroll
        for (int m = 0; m < 2; ++m)
            #pragma unroll
            for (int r = 0; r < 4; ++r)
                se[m][r] += __shfl_xor(se[m][r], mask);
    if (r16 == 0) {
        #pragma unroll
        for (int m = 0; m < 2; ++m) {
            const size_t o = (size_t)blockIdx.y * NTOT + rowBase + m * 16 + q * 4;
            f32x4 vs;
            #pragma unroll
            for (int r = 0; r < 4; ++r) vs[r] = se[m][r];
            *(f32x4*)(pSe + o) = vs;
        }
    }
}

// K4: per-row loss (hist + chunk-sum + self-correction + analytic pos-dot) +
// block partial + atomic accumulate to out. 32 x 256.
__global__ __launch_bounds__(256) void finalize_kernel(
    const unsigned short* __restrict__ Bg, const int* __restrict__ labT,
    const float* __restrict__ S, const float* __restrict__ pSe,
    float* __restrict__ out)
{
    __shared__ int hist[NCLASS];
    const int t = threadIdx.x;
    if (t < NCLASS) hist[t] = 0;
    __syncthreads();
    #pragma unroll
    for (int i = 0; i < NTOT / 256; ++i)
        atomicAdd(&hist[labT[i * 256 + t]], 1);
    __syncthreads();

    const int row = blockIdx.x * 256 + t;
    const int lab = labT[row];
    float se = 0.f;
    #pragma unroll
    for (int ch = 0; ch < NCHUNK; ++ch) se += pSe[(size_t)ch * NTOT + row];

    // d1 = a.S_lab, d2 = a.a (self), in fp32 from bf16
    const unsigned short* ar = Bg + (size_t)row * DDIM;
    const float* sr = S + lab * DDIM;
    float d1 = 0.f, d2 = 0.f;
    #pragma unroll 4
    for (int i = 0; i < 32; ++i) {
        bf16x8 av = *(const bf16x8*)(ar + i * 8);
        f32x4 s0 = *(const f32x4*)(sr + i * 8);
        f32x4 s1 = *(const f32x4*)(sr + i * 8 + 4);
        #pragma unroll
        for (int j = 0; j < 4; ++j) {
            float a = (float)av[j];
            d1 = fmaf(a, s0[j], d1); d2 = fmaf(a, a, d2);
        }
        #pragma unroll
        for (int j = 0; j < 4; ++j) {
            float a = (float)av[4 + j];
            d1 = fmaf(a, s1[j], d1); d2 = fmaf(a, a, d2);
        }
    }
    se -= __builtin_amdgcn_exp2f(fmaf(d2, K1, BIASS));   // remove self-contrast term
    const float pc = (float)(hist[lab] - 1);
    float loss = EPI_T + __logf(se) - INV_T * (d1 - d2) / pc;

    #pragma unroll
    for (int mask = 1; mask < 64; mask <<= 1) loss += __shfl_xor(loss, mask);
    __shared__ float red[4];
    if ((t & 63) == 0) red[t >> 6] = loss;
    __syncthreads();
    if (t == 0)
        atomicAdd(out, (red[0] + red[1] + red[2] + red[3]) * (1.f / (float)NTOT));
}

extern "C" void kernel_launch(void* const* d_in, const int* in_sizes, int n_in,
                              void* d_out, int out_size, void* d_ws, size_t ws_size,
                              hipStream_t stream) {
    const float* feat = (const float*)d_in[0];
    const int* labels = (const int*)d_in[1];
    float* out = (float*)d_out;

    char* ws = (char*)d_ws;
    unsigned short* Bg = (unsigned short*)ws;                        // 4 MB
    int* labT = (int*)(ws + (4u << 20));                             // 32 KB
    float* S = (float*)(ws + (4u << 20) + (64u << 10));              // 100 KB
    float* pSe = (float*)(ws + (4u << 20) + (192u << 10));           // 512 KB

    prep_kernel<<<2048, 256, 0, stream>>>(feat, labels, Bg, labT, out);
    classsum_kernel<<<NCLASS, 256, 0, stream>>>(Bg, labT, S);
    dim3 grid(64, NCHUNK);
    supcon_main<<<grid, 256, 0, stream>>>(Bg, labT, pSe);
    finalize_kernel<<<32, 256, 0, stream>>>(Bg, labT, S, pSe, out);
}